// Round 1
// baseline (71.768 us; speedup 1.0000x reference)
//
#include <hip/hip_runtime.h>
#include <hip/hip_bf16.h>

typedef __bf16 bf16;
typedef __bf16 bf16x4 __attribute__((ext_vector_type(4)));
typedef __bf16 bf16x8 __attribute__((ext_vector_type(8)));
typedef float f32x4 __attribute__((ext_vector_type(4)));

#define NEGV -9.0e15f

// ---------------- converts ----------------

__global__ __launch_bounds__(256) void k_convert(const float* __restrict__ src,
                                                 bf16* __restrict__ dst, int n) {
  int i = (blockIdx.x * 256 + threadIdx.x) * 4;
  if (i >= n) return;
  float4 v = *(const float4*)(src + i);
  bf16x4 o;
  o[0] = (bf16)v.x; o[1] = (bf16)v.y; o[2] = (bf16)v.z; o[3] = (bf16)v.w;
  *(bf16x4*)(dst + i) = o;
}

// dst[N][512] = src[512][N] transposed + bf16
__global__ __launch_bounds__(256) void k_transpose512(const float* __restrict__ src,
                                                      bf16* __restrict__ dst, int N) {
  int i = blockIdx.x * 256 + threadIdx.x;
  int n = i >> 9, k = i & 511;
  dst[i] = (bf16)src[k * N + n];
}

// ---------------- GEMM 1: qkv = x @ Wqkv + b, scatter to Q/K/V^T ----------------
// A [4096][512] bf16 row-major, BT [1536][512] bf16 (Wqkv^T)

__global__ __launch_bounds__(256) void k_gemm_qkv(
    const bf16* __restrict__ A, const bf16* __restrict__ BT, const float* __restrict__ bias,
    bf16* __restrict__ Qb, bf16* __restrict__ Kb, bf16* __restrict__ VTb) {
  __shared__ __align__(16) char As[128 * 128];
  __shared__ __align__(16) char Bs[128 * 128];
  const int m0 = blockIdx.x * 128, n0 = blockIdx.y * 128;
  const int tid = threadIdx.x, wave = tid >> 6, lane = tid & 63;
  const int wr = (wave >> 1) * 64, wc = (wave & 1) * 64;
  const int lr = lane & 15, lg = lane >> 4;
  f32x4 acc[4][4] = {};

  for (int kt = 0; kt < 512; kt += 64) {
    __syncthreads();
    for (int c = tid; c < 1024; c += 256) {
      int row = c >> 3, colb = (c & 7) << 4;
      int sw = colb ^ ((row & 7) << 4);
      *(uint4*)(As + row * 128 + sw) =
          *(const uint4*)((const char*)A + (size_t)(m0 + row) * 1024 + kt * 2 + colb);
      *(uint4*)(Bs + row * 128 + sw) =
          *(const uint4*)((const char*)BT + (size_t)(n0 + row) * 1024 + kt * 2 + colb);
    }
    __syncthreads();
    for (int kk = 0; kk < 2; ++kk) {
      bf16x8 af[4], bfr[4];
      int colb = kk * 64 + lg * 16;
      for (int m = 0; m < 4; ++m) {
        int row = wr + m * 16 + lr;
        af[m] = *(const bf16x8*)(As + row * 128 + (colb ^ ((row & 7) << 4)));
      }
      for (int n = 0; n < 4; ++n) {
        int row = wc + n * 16 + lr;
        bfr[n] = *(const bf16x8*)(Bs + row * 128 + (colb ^ ((row & 7) << 4)));
      }
      for (int m = 0; m < 4; ++m)
        for (int n = 0; n < 4; ++n)
          acc[m][n] = __builtin_amdgcn_mfma_f32_16x16x32_bf16(af[m], bfr[n], acc[m][n], 0, 0, 0);
    }
  }

  for (int m = 0; m < 4; ++m)
    for (int n = 0; n < 4; ++n)
      for (int r = 0; r < 4; ++r) {
        int gm = m0 + wr + m * 16 + lg * 4 + r;
        int gn = n0 + wc + n * 16 + lr;
        float v = acc[m][n][r] + bias[gn];
        bf16 bv = (bf16)v;
        int b = gm >> 11, s = gm & 2047;
        int h = gn / 192, rr2 = gn - h * 192, sel = rr2 >> 6, d = rr2 & 63;
        size_t bh = (size_t)(b * 8 + h);
        if (sel == 0)      Qb[(bh * 2048 + s) * 64 + d] = bv;
        else if (sel == 1) Kb[(bh * 2048 + s) * 64 + d] = bv;
        else               VTb[(bh * 64 + d) * 2048 + s] = bv;
      }
}

// ---------------- attention ----------------
// grid (32 qblocks, 16 b*h), 256 threads (4 waves), each wave: 16 query rows

__global__ __launch_bounds__(256) void k_attn(
    const bf16* __restrict__ Qb, const bf16* __restrict__ Kb, const bf16* __restrict__ VTb,
    const int* __restrict__ pmask, bf16* __restrict__ AO) {
  __shared__ __align__(16) char Qs[64 * 128];
  __shared__ __align__(16) char Ks[128 * 128];
  __shared__ __align__(16) char VTs[64 * 256];
  __shared__ __align__(16) char Ps[64 * 256];
  __shared__ float pmk[128];

  const int qb = blockIdx.x, bh = blockIdx.y;
  const int b = bh >> 3, h = bh & 7;
  const int q0 = qb * 64, kstart = q0 - 32;
  const int tid = threadIdx.x, wave = tid >> 6, lane = tid & 63;
  const int lr = lane & 15, lg = lane >> 4;

  const bf16* Qg = Qb + (size_t)bh * (2048 * 64);
  const bf16* Kg = Kb + (size_t)bh * (2048 * 64);
  const bf16* Vg = VTb + (size_t)bh * (64 * 2048);

  for (int c = tid; c < 512; c += 256) {
    int row = c >> 3, colb = (c & 7) << 4;
    *(uint4*)(Qs + row * 128 + (colb ^ ((row & 7) << 4))) =
        *(const uint4*)((const char*)Qg + (size_t)(q0 + row) * 128 + colb);
  }
  for (int c = tid; c < 1024; c += 256) {
    int row = c >> 3, colb = (c & 7) << 4;
    int sk = kstart + row;
    sk = sk < 0 ? 0 : (sk > 2047 ? 2047 : sk);
    *(uint4*)(Ks + row * 128 + (colb ^ ((row & 7) << 4))) =
        *(const uint4*)((const char*)Kg + (size_t)sk * 128 + colb);
  }
  for (int c = tid; c < 1024; c += 256) {
    int d = c >> 4, colb = (c & 15) << 4;
    int sl = kstart + (colb >> 1);
    sl = sl < 0 ? 0 : (sl > 2040 ? 2040 : sl);
    *(uint4*)(VTs + d * 256 + (colb ^ ((d & 7) << 4))) =
        *(const uint4*)((const char*)Vg + (size_t)d * 4096 + (size_t)sl * 2);
  }
  if (tid < 128) {
    int sk = kstart + tid;
    pmk[tid] = (sk >= 0 && sk < 2048 && pmask[b * 2048 + sk] != 0) ? 1.0f : 0.0f;
  }
  __syncthreads();

  // scores S = Q·K^T : 16 rows x 128 keys per wave
  f32x4 sc[8] = {};
  for (int kk = 0; kk < 2; ++kk) {
    int colb = kk * 64 + lg * 16;
    int qrow = wave * 16 + lr;
    bf16x8 qf = *(const bf16x8*)(Qs + qrow * 128 + (colb ^ ((qrow & 7) << 4)));
    for (int nt = 0; nt < 8; ++nt) {
      int krow = nt * 16 + lr;
      bf16x8 kf = *(const bf16x8*)(Ks + krow * 128 + (colb ^ ((krow & 7) << 4)));
      sc[nt] = __builtin_amdgcn_mfma_f32_16x16x32_bf16(qf, kf, sc[nt], 0, 0, 0);
    }
  }

  // mask + scale; rows held by this lane: qrow = wave*16 + lg*4 + r, col j = nt*16 + lr
  float rmax[4] = {NEGV, NEGV, NEGV, NEGV};
  for (int nt = 0; nt < 8; ++nt) {
    int j = nt * 16 + lr;
    float pk = pmk[j];
    for (int r = 0; r < 4; ++r) {
      int qrow = wave * 16 + lg * 4 + r;
      float v = sc[nt][r] * 0.125f;
      v = (j >= qrow && j <= qrow + 64 && pk > 0.5f) ? v : NEGV;
      sc[nt][r] = v;
      rmax[r] = fmaxf(rmax[r], v);
    }
  }
  for (int off = 1; off < 16; off <<= 1)
    for (int r = 0; r < 4; ++r)
      rmax[r] = fmaxf(rmax[r], __shfl_xor(rmax[r], off));

  float rsum[4] = {0.f, 0.f, 0.f, 0.f};
  for (int nt = 0; nt < 8; ++nt)
    for (int r = 0; r < 4; ++r) {
      float p = __expf(sc[nt][r] - rmax[r]);
      sc[nt][r] = p;
      rsum[r] += p;
    }
  for (int off = 1; off < 16; off <<= 1)
    for (int r = 0; r < 4; ++r)
      rsum[r] += __shfl_xor(rsum[r], off);

  // unnormalized P -> LDS (bf16)
  for (int nt = 0; nt < 8; ++nt)
    for (int r = 0; r < 4; ++r) {
      int qrow = wave * 16 + lg * 4 + r;
      int colb = (nt * 16 + lr) * 2;
      *(bf16*)(Ps + qrow * 256 + (colb ^ ((qrow & 7) << 4))) = (bf16)sc[nt][r];
    }
  __syncthreads();

  // O = P·V : 16 rows x 64 d per wave, K=128
  f32x4 oacc[4] = {};
  for (int ks = 0; ks < 4; ++ks) {
    int colb = ks * 64 + lg * 16;
    int prow = wave * 16 + lr;
    bf16x8 pf = *(const bf16x8*)(Ps + prow * 256 + (colb ^ ((prow & 7) << 4)));
    for (int n = 0; n < 4; ++n) {
      int vrow = n * 16 + lr;
      bf16x8 vf = *(const bf16x8*)(VTs + vrow * 256 + (colb ^ ((vrow & 7) << 4)));
      oacc[n] = __builtin_amdgcn_mfma_f32_16x16x32_bf16(pf, vf, oacc[n], 0, 0, 0);
    }
  }

  float inv[4];
  for (int r = 0; r < 4; ++r) inv[r] = 1.0f / rsum[r];
  for (int r = 0; r < 4; ++r) {
    int qrow = wave * 16 + lg * 4 + r;
    float pq = (pmask[b * 2048 + q0 + qrow] != 0) ? 1.0f : 0.0f;
    float s2 = inv[r] * pq;
    for (int n = 0; n < 4; ++n)
      AO[(size_t)(b * 2048 + q0 + qrow) * 512 + h * 64 + n * 16 + lr] = (bf16)(oacc[n][r] * s2);
  }
}

// ---------------- GEMM 2: out = AO @ Wo + bo (fp32 out) ----------------

__global__ __launch_bounds__(256) void k_gemm_out(
    const bf16* __restrict__ A, const bf16* __restrict__ BT, const float* __restrict__ bias,
    float* __restrict__ C) {
  __shared__ __align__(16) char As[128 * 128];
  __shared__ __align__(16) char Bs[128 * 128];
  const int m0 = blockIdx.x * 128, n0 = blockIdx.y * 128;
  const int tid = threadIdx.x, wave = tid >> 6, lane = tid & 63;
  const int wr = (wave >> 1) * 64, wc = (wave & 1) * 64;
  const int lr = lane & 15, lg = lane >> 4;
  f32x4 acc[4][4] = {};

  for (int kt = 0; kt < 512; kt += 64) {
    __syncthreads();
    for (int c = tid; c < 1024; c += 256) {
      int row = c >> 3, colb = (c & 7) << 4;
      int sw = colb ^ ((row & 7) << 4);
      *(uint4*)(As + row * 128 + sw) =
          *(const uint4*)((const char*)A + (size_t)(m0 + row) * 1024 + kt * 2 + colb);
      *(uint4*)(Bs + row * 128 + sw) =
          *(const uint4*)((const char*)BT + (size_t)(n0 + row) * 1024 + kt * 2 + colb);
    }
    __syncthreads();
    for (int kk = 0; kk < 2; ++kk) {
      bf16x8 af[4], bfr[4];
      int colb = kk * 64 + lg * 16;
      for (int m = 0; m < 4; ++m) {
        int row = wr + m * 16 + lr;
        af[m] = *(const bf16x8*)(As + row * 128 + (colb ^ ((row & 7) << 4)));
      }
      for (int n = 0; n < 4; ++n) {
        int row = wc + n * 16 + lr;
        bfr[n] = *(const bf16x8*)(Bs + row * 128 + (colb ^ ((row & 7) << 4)));
      }
      for (int m = 0; m < 4; ++m)
        for (int n = 0; n < 4; ++n)
          acc[m][n] = __builtin_amdgcn_mfma_f32_16x16x32_bf16(af[m], bfr[n], acc[m][n], 0, 0, 0);
    }
  }

  for (int m = 0; m < 4; ++m)
    for (int n = 0; n < 4; ++n)
      for (int r = 0; r < 4; ++r) {
        int gm = m0 + wr + m * 16 + lg * 4 + r;
        int gn = n0 + wc + n * 16 + lr;
        C[(size_t)gm * 512 + gn] = acc[m][n][r] + bias[gn];
      }
}

// ---------------- launch ----------------

extern "C" void kernel_launch(void* const* d_in, const int* in_sizes, int n_in,
                              void* d_out, int out_size, void* d_ws, size_t ws_size,
                              hipStream_t stream) {
  const float* x     = (const float*)d_in[0];
  const int*   pmask = (const int*)d_in[1];
  const float* Wqkv  = (const float*)d_in[2];
  const float* bqkv  = (const float*)d_in[3];
  const float* Wo    = (const float*)d_in[4];
  const float* bo    = (const float*)d_in[5];
  float* out = (float*)d_out;

  char* ws = (char*)d_ws;
  bf16* xb    = (bf16*)(ws);                 // 4096*512*2   = 4 MiB
  bf16* WqkvT = (bf16*)(ws + 4194304);       // 1536*512*2   = 1.5 MiB
  bf16* WoT   = (bf16*)(ws + 5767168);       // 512*512*2    = 0.5 MiB
  bf16* Qb    = (bf16*)(ws + 6291456);       // [b][h][s][d] = 4 MiB
  bf16* Kb    = (bf16*)(ws + 10485760);      // [b][h][s][d] = 4 MiB
  bf16* VTb   = (bf16*)(ws + 14680064);      // [b][h][d][s] = 4 MiB
  bf16* AO    = (bf16*)(ws + 18874368);      // [b][s][h*d]  = 4 MiB

  k_convert<<<2048, 256, 0, stream>>>(x, xb, 2097152);
  k_transpose512<<<3072, 256, 0, stream>>>(Wqkv, WqkvT, 1536);
  k_transpose512<<<1024, 256, 0, stream>>>(Wo, WoT, 512);

  dim3 g1(32, 12);
  k_gemm_qkv<<<g1, 256, 0, stream>>>(xb, WqkvT, bqkv, Qb, Kb, VTb);

  dim3 ga(32, 16);
  k_attn<<<ga, 256, 0, stream>>>(Qb, Kb, VTb, pmask, AO);

  dim3 g2(32, 4);
  k_gemm_out<<<g2, 256, 0, stream>>>(AO, WoT, bo, out);
}

// Round 2
// 47.838 us; speedup vs baseline: 1.5002x; 1.5002x over previous
//
#include <hip/hip_runtime.h>
#include <hip/hip_bf16.h>

typedef __bf16 bf16;
typedef __bf16 bf16x4 __attribute__((ext_vector_type(4)));
typedef __bf16 bf16x8 __attribute__((ext_vector_type(8)));
typedef float f32x4 __attribute__((ext_vector_type(4)));

#define NEGV -9.0e15f

#define GLD16(gp, lp)                                                    \
  __builtin_amdgcn_global_load_lds(                                     \
      (const __attribute__((address_space(1))) void*)(gp),              \
      (__attribute__((address_space(3))) void*)(lp), 16, 0, 0)

// ---------------- prep: x->bf16, Wqkv^T, Wo^T (one launch) ----------------

__global__ __launch_bounds__(256) void k_prep(
    const float* __restrict__ x, const float* __restrict__ Wqkv, const float* __restrict__ Wo,
    bf16* __restrict__ xb, bf16* __restrict__ WqkvT, bf16* __restrict__ WoT) {
  const int bid = blockIdx.x, tid = threadIdx.x;
  if (bid < 2048) {               // x convert: 2048 * 1024 floats
    int i = bid * 1024 + tid * 4;
    float4 v = *(const float4*)(x + i);
    bf16x4 o;
    o[0] = (bf16)v.x; o[1] = (bf16)v.y; o[2] = (bf16)v.z; o[3] = (bf16)v.w;
    *(bf16x4*)(xb + i) = o;
    return;
  }
  __shared__ float tl[32][33];
  const float* src; bf16* dst; int N, t;
  if (bid < 2816) { t = bid - 2048; src = Wqkv; dst = WqkvT; N = 1536; }
  else            { t = bid - 2816; src = Wo;   dst = WoT;   N = 512;  }
  const int tk = t & 15, tn = t >> 4;      // k-tile (512/32), n-tile
  const int c = tid & 31, r0 = tid >> 5;   // 8 rows/pass
  for (int rr = 0; rr < 4; ++rr) {
    int row = r0 + rr * 8;                 // k within tile
    tl[row][c] = src[(size_t)(tk * 32 + row) * N + tn * 32 + c];
  }
  __syncthreads();
  for (int rr = 0; rr < 4; ++rr) {
    int row = r0 + rr * 8;                 // n within tile
    dst[(size_t)(tn * 32 + row) * 512 + tk * 32 + c] = (bf16)tl[c][row];
  }
}

// ---------------- GEMM 1: qkv = x @ Wqkv + b, scatter to Q/K/V^T ----------------
// A [4096][512] bf16, BT [1536][512] bf16. BM=128, BN=64, BK=64.
// m97 structure: global_load_lds width-16 staging, linear LDS, 2-barrier loop.

__global__ __launch_bounds__(256) void k_gemm_qkv(
    const bf16* __restrict__ A, const bf16* __restrict__ BT, const float* __restrict__ bias,
    bf16* __restrict__ Qb, bf16* __restrict__ Kb, bf16* __restrict__ VTb) {
  __shared__ __align__(16) char As[16384];   // [128 rows][64 bf16]
  __shared__ __align__(16) char Bs[8192];    // [64 rows][64 bf16]
  const int m0 = blockIdx.x * 128, n0 = blockIdx.y * 64;
  const int tid = threadIdx.x, wave = tid >> 6, lane = tid & 63;
  const int wr = (wave >> 1) * 64, wc = (wave & 1) * 32;
  const int lr = lane & 15, lg = lane >> 4;
  const int srow = lane >> 3, scolb = (lane & 7) << 4;
  const char* Ab = (const char*)A;
  const char* Bb = (const char*)BT;
  f32x4 acc[4][2] = {};

  for (int kt = 0; kt < 512; kt += 64) {
    __syncthreads();
    for (int t = 0; t < 4; ++t) {
      int chunk = wave * 4 + t;                       // 0..15, 8 rows each
      GLD16(Ab + (size_t)(m0 + chunk * 8 + srow) * 1024 + kt * 2 + scolb,
            As + chunk * 1024);
    }
    for (int t = 0; t < 2; ++t) {
      int chunk = wave * 2 + t;                       // 0..7
      GLD16(Bb + (size_t)(n0 + chunk * 8 + srow) * 1024 + kt * 2 + scolb,
            Bs + chunk * 1024);
    }
    __syncthreads();
    for (int kk = 0; kk < 2; ++kk) {
      bf16x8 af[4], bfr[2];
      for (int m = 0; m < 4; ++m)
        af[m] = *(const bf16x8*)(As + (wr + m * 16 + lr) * 128 + kk * 64 + lg * 16);
      for (int n = 0; n < 2; ++n)
        bfr[n] = *(const bf16x8*)(Bs + (wc + n * 16 + lr) * 128 + kk * 64 + lg * 16);
      for (int m = 0; m < 4; ++m)
        for (int n = 0; n < 2; ++n)
          acc[m][n] = __builtin_amdgcn_mfma_f32_16x16x32_bf16(af[m], bfr[n], acc[m][n], 0, 0, 0);
    }
  }

  float bv0 = bias[n0 + wc + lr], bv1 = bias[n0 + wc + 16 + lr];
  for (int m = 0; m < 4; ++m)
    for (int n = 0; n < 2; ++n)
      for (int r = 0; r < 4; ++r) {
        int gm = m0 + wr + m * 16 + lg * 4 + r;
        int gn = n0 + wc + n * 16 + lr;
        float v = acc[m][n][r] + (n ? bv1 : bv0);
        bf16 bvv = (bf16)v;
        int b = gm >> 11, s = gm & 2047;
        int h = gn / 192, rr2 = gn - h * 192, sel = rr2 >> 6, d = rr2 & 63;
        size_t bh = (size_t)(b * 8 + h);
        if (sel == 0)      Qb[(bh * 2048 + s) * 64 + d] = bvv;
        else if (sel == 1) Kb[(bh * 2048 + s) * 64 + d] = bvv;
        else               VTb[(bh * 64 + d) * 2048 + s] = bvv;
      }
}

// ---------------- attention ----------------
// grid (32 qblocks, 16 b*h), 256 threads (4 waves), each wave: 16 query rows

__global__ __launch_bounds__(256) void k_attn(
    const bf16* __restrict__ Qb, const bf16* __restrict__ Kb, const bf16* __restrict__ VTb,
    const int* __restrict__ pmask, bf16* __restrict__ AO) {
  __shared__ __align__(16) char Qs[64 * 128];
  __shared__ __align__(16) char Ks[128 * 128];
  __shared__ __align__(16) char VTs[64 * 256];
  __shared__ __align__(16) char Ps[64 * 256];
  __shared__ float pmk[128];

  const int qb = blockIdx.x, bh = blockIdx.y;
  const int b = bh >> 3, h = bh & 7;
  const int q0 = qb * 64, kstart = q0 - 32;
  const int tid = threadIdx.x, wave = tid >> 6, lane = tid & 63;
  const int lr = lane & 15, lg = lane >> 4;

  const bf16* Qg = Qb + (size_t)bh * (2048 * 64);
  const bf16* Kg = Kb + (size_t)bh * (2048 * 64);
  const bf16* Vg = VTb + (size_t)bh * (64 * 2048);

  for (int c = tid; c < 512; c += 256) {
    int row = c >> 3, colb = (c & 7) << 4;
    *(uint4*)(Qs + row * 128 + (colb ^ ((row & 7) << 4))) =
        *(const uint4*)((const char*)Qg + (size_t)(q0 + row) * 128 + colb);
  }
  for (int c = tid; c < 1024; c += 256) {
    int row = c >> 3, colb = (c & 7) << 4;
    int sk = kstart + row;
    sk = sk < 0 ? 0 : (sk > 2047 ? 2047 : sk);
    *(uint4*)(Ks + row * 128 + (colb ^ ((row & 7) << 4))) =
        *(const uint4*)((const char*)Kg + (size_t)sk * 128 + colb);
  }
  for (int c = tid; c < 1024; c += 256) {
    int d = c >> 4, colb = (c & 15) << 4;
    int sl = kstart + (colb >> 1);
    sl = sl < 0 ? 0 : (sl > 2040 ? 2040 : sl);
    *(uint4*)(VTs + d * 256 + (colb ^ ((d & 7) << 4))) =
        *(const uint4*)((const char*)Vg + (size_t)d * 4096 + (size_t)sl * 2);
  }
  if (tid < 128) {
    int sk = kstart + tid;
    pmk[tid] = (sk >= 0 && sk < 2048 && pmask[b * 2048 + sk] != 0) ? 1.0f : 0.0f;
  }
  __syncthreads();

  // scores S = Q·K^T : 16 rows x 128 keys per wave
  f32x4 sc[8] = {};
  for (int kk = 0; kk < 2; ++kk) {
    int colb = kk * 64 + lg * 16;
    int qrow = wave * 16 + lr;
    bf16x8 qf = *(const bf16x8*)(Qs + qrow * 128 + (colb ^ ((qrow & 7) << 4)));
    for (int nt = 0; nt < 8; ++nt) {
      int krow = nt * 16 + lr;
      bf16x8 kf = *(const bf16x8*)(Ks + krow * 128 + (colb ^ ((krow & 7) << 4)));
      sc[nt] = __builtin_amdgcn_mfma_f32_16x16x32_bf16(qf, kf, sc[nt], 0, 0, 0);
    }
  }

  float rmax[4] = {NEGV, NEGV, NEGV, NEGV};
  for (int nt = 0; nt < 8; ++nt) {
    int j = nt * 16 + lr;
    float pk = pmk[j];
    for (int r = 0; r < 4; ++r) {
      int qrow = wave * 16 + lg * 4 + r;
      float v = sc[nt][r] * 0.125f;
      v = (j >= qrow && j <= qrow + 64 && pk > 0.5f) ? v : NEGV;
      sc[nt][r] = v;
      rmax[r] = fmaxf(rmax[r], v);
    }
  }
  for (int off = 1; off < 16; off <<= 1)
    for (int r = 0; r < 4; ++r)
      rmax[r] = fmaxf(rmax[r], __shfl_xor(rmax[r], off));

  float rsum[4] = {0.f, 0.f, 0.f, 0.f};
  for (int nt = 0; nt < 8; ++nt)
    for (int r = 0; r < 4; ++r) {
      float p = __expf(sc[nt][r] - rmax[r]);
      sc[nt][r] = p;
      rsum[r] += p;
    }
  for (int off = 1; off < 16; off <<= 1)
    for (int r = 0; r < 4; ++r)
      rsum[r] += __shfl_xor(rsum[r], off);

  for (int nt = 0; nt < 8; ++nt)
    for (int r = 0; r < 4; ++r) {
      int qrow = wave * 16 + lg * 4 + r;
      int colb = (nt * 16 + lr) * 2;
      *(bf16*)(Ps + qrow * 256 + (colb ^ ((qrow & 7) << 4))) = (bf16)sc[nt][r];
    }
  __syncthreads();

  // O = P·V : 16 rows x 64 d per wave, K=128
  f32x4 oacc[4] = {};
  for (int ks = 0; ks < 4; ++ks) {
    int colb = ks * 64 + lg * 16;
    int prow = wave * 16 + lr;
    bf16x8 pf = *(const bf16x8*)(Ps + prow * 256 + (colb ^ ((prow & 7) << 4)));
    for (int n = 0; n < 4; ++n) {
      int vrow = n * 16 + lr;
      bf16x8 vf = *(const bf16x8*)(VTs + vrow * 256 + (colb ^ ((vrow & 7) << 4)));
      oacc[n] = __builtin_amdgcn_mfma_f32_16x16x32_bf16(pf, vf, oacc[n], 0, 0, 0);
    }
  }

  float inv[4];
  for (int r = 0; r < 4; ++r) inv[r] = 1.0f / rsum[r];
  for (int r = 0; r < 4; ++r) {
    int qrow = wave * 16 + lg * 4 + r;
    float pq = (pmask[b * 2048 + q0 + qrow] != 0) ? 1.0f : 0.0f;
    float s2 = inv[r] * pq;
    for (int n = 0; n < 4; ++n)
      AO[(size_t)(b * 2048 + q0 + qrow) * 512 + h * 64 + n * 16 + lr] = (bf16)(oacc[n][r] * s2);
  }
}

// ---------------- GEMM 2: out = AO @ Wo + bo (fp32 out), BM=128 BN=64 ----------------

__global__ __launch_bounds__(256) void k_gemm_out(
    const bf16* __restrict__ A, const bf16* __restrict__ BT, const float* __restrict__ bias,
    float* __restrict__ C) {
  __shared__ __align__(16) char As[16384];
  __shared__ __align__(16) char Bs[8192];
  const int m0 = blockIdx.x * 128, n0 = blockIdx.y * 64;
  const int tid = threadIdx.x, wave = tid >> 6, lane = tid & 63;
  const int wr = (wave >> 1) * 64, wc = (wave & 1) * 32;
  const int lr = lane & 15, lg = lane >> 4;
  const int srow = lane >> 3, scolb = (lane & 7) << 4;
  const char* Ab = (const char*)A;
  const char* Bb = (const char*)BT;
  f32x4 acc[4][2] = {};

  for (int kt = 0; kt < 512; kt += 64) {
    __syncthreads();
    for (int t = 0; t < 4; ++t) {
      int chunk = wave * 4 + t;
      GLD16(Ab + (size_t)(m0 + chunk * 8 + srow) * 1024 + kt * 2 + scolb,
            As + chunk * 1024);
    }
    for (int t = 0; t < 2; ++t) {
      int chunk = wave * 2 + t;
      GLD16(Bb + (size_t)(n0 + chunk * 8 + srow) * 1024 + kt * 2 + scolb,
            Bs + chunk * 1024);
    }
    __syncthreads();
    for (int kk = 0; kk < 2; ++kk) {
      bf16x8 af[4], bfr[2];
      for (int m = 0; m < 4; ++m)
        af[m] = *(const bf16x8*)(As + (wr + m * 16 + lr) * 128 + kk * 64 + lg * 16);
      for (int n = 0; n < 2; ++n)
        bfr[n] = *(const bf16x8*)(Bs + (wc + n * 16 + lr) * 128 + kk * 64 + lg * 16);
      for (int m = 0; m < 4; ++m)
        for (int n = 0; n < 2; ++n)
          acc[m][n] = __builtin_amdgcn_mfma_f32_16x16x32_bf16(af[m], bfr[n], acc[m][n], 0, 0, 0);
    }
  }

  float bv0 = bias[n0 + wc + lr], bv1 = bias[n0 + wc + 16 + lr];
  for (int m = 0; m < 4; ++m)
    for (int n = 0; n < 2; ++n)
      for (int r = 0; r < 4; ++r) {
        int gm = m0 + wr + m * 16 + lg * 4 + r;
        int gn = n0 + wc + n * 16 + lr;
        C[(size_t)gm * 512 + gn] = acc[m][n][r] + (n ? bv1 : bv0);
      }
}

// ---------------- launch ----------------

extern "C" void kernel_launch(void* const* d_in, const int* in_sizes, int n_in,
                              void* d_out, int out_size, void* d_ws, size_t ws_size,
                              hipStream_t stream) {
  const float* x     = (const float*)d_in[0];
  const int*   pmask = (const int*)d_in[1];
  const float* Wqkv  = (const float*)d_in[2];
  const float* bqkv  = (const float*)d_in[3];
  const float* Wo    = (const float*)d_in[4];
  const float* bo    = (const float*)d_in[5];
  float* out = (float*)d_out;

  char* ws = (char*)d_ws;
  bf16* xb    = (bf16*)(ws);                 // 4096*512*2   = 4 MiB
  bf16* WqkvT = (bf16*)(ws + 4194304);       // 1536*512*2   = 1.5 MiB
  bf16* WoT   = (bf16*)(ws + 5767168);       // 512*512*2    = 0.5 MiB
  bf16* Qb    = (bf16*)(ws + 6291456);       // [b][h][s][d] = 4 MiB
  bf16* Kb    = (bf16*)(ws + 10485760);      // [b][h][s][d] = 4 MiB
  bf16* VTb   = (bf16*)(ws + 14680064);      // [b][h][d][s] = 4 MiB
  bf16* AO    = (bf16*)(ws + 18874368);      // [b][s][h*d]  = 4 MiB

  k_prep<<<3072, 256, 0, stream>>>(x, Wqkv, Wo, xb, WqkvT, WoT);

  dim3 g1(32, 24);
  k_gemm_qkv<<<g1, 256, 0, stream>>>(xb, WqkvT, bqkv, Qb, Kb, VTb);

  dim3 ga(32, 16);
  k_attn<<<ga, 256, 0, stream>>>(Qb, Kb, VTb, pmask, AO);

  dim3 g2(32, 8);
  k_gemm_out<<<g2, 256, 0, stream>>>(AO, WoT, bo, out);
}